// Round 6
// baseline (508.739 us; speedup 1.0000x reference)
//
#include <hip/hip_runtime.h>
#include <math.h>

#define DM 512          // d_model
#define NQ 16           // num output queries
#define NG (NQ + 1)     // 16 score rows + 1 pooled-v row
#define NR (NG + 2)     // 19 partial rows: S1, S2, acc[0..16]

typedef __attribute__((ext_vector_type(2))) float f32x2;
typedef __attribute__((ext_vector_type(4))) float f32x4;   // clang-native: OK for nontemporal builtins

__device__ __forceinline__ float wave_reduce_sum(float v) {
    #pragma unroll
    for (int off = 32; off > 0; off >>= 1) v += __shfl_xor(v, off, 64);
    return v;
}
__device__ __forceinline__ float wave_reduce_max(float v) {
    #pragma unroll
    for (int off = 32; off > 0; off >>= 1) v = fmaxf(v, __shfl_xor(v, off, 64));
    return v;
}

// --- K1: fused independent precompute --------------------------------------
// blocks 0..127   : PET[d][n] generation (block 0 also zeroes consts + cnt)
// blocks 128..255 : LDS-tiled transpose Wk->WkT, Wv->WvT
// blocks 256..2303: qh[q][e] = LN(query[q]*scale) . Wq[e] + bq[e]
__global__ void k1_setup(const float* __restrict__ Wk, const float* __restrict__ Wv,
                         const float* __restrict__ query,
                         const float* __restrict__ ln_q_w, const float* __restrict__ ln_q_b,
                         const float* __restrict__ Wq, const float* __restrict__ bq,
                         float* __restrict__ PET, float* __restrict__ WkT,
                         float* __restrict__ WvT, float* __restrict__ qh,
                         float* __restrict__ consts, int* __restrict__ cnt,
                         int N, int B) {
    __shared__ float tile[64][65];
    int bx = blockIdx.x;
    int lane = threadIdx.x & 63;
    int w = threadIdx.x >> 6;

    if (bx < 128) {                       // --- PET (+ zero init on block 0) ---
        if (bx == 0) {
            int tid = threadIdx.x;
            if (tid < 34) consts[tid] = 0.f;
            for (int i = tid; i < B; i += 256) cnt[i] = 0;
        }
        int ntile = bx & 7, jg = bx >> 3;
        int n = ntile * 64 + lane;
        float p = (float)(N - 1 - n);     // reversed PE
        const float c = -logf(10000.f) / (float)DM;
        int jbase = jg * 16 + w * 4;
        #pragma unroll
        for (int u = 0; u < 4; ++u) {
            int j = jbase + u;
            float wj = expf((float)(2 * j) * c);
            float ang = p * wj;
            PET[(size_t)(2 * j) * N + n] = sinf(ang);
            PET[(size_t)(2 * j + 1) * N + n] = cosf(ang);
        }
    } else if (bx < 256) {                // --- transpose ---
        int t = bx - 128;
        const float* W = (t >> 6) ? Wv : Wk;
        float* WT = (t >> 6) ? WvT : WkT;
        int tl = t & 63;
        int te = tl >> 3, td = tl & 7;    // 8x8 tiles of 64x64
        #pragma unroll
        for (int i = 0; i < 16; ++i) {
            int el = w * 16 + i;
            tile[el][lane] = W[(size_t)(te * 64 + el) * DM + td * 64 + lane];
        }
        __syncthreads();
        #pragma unroll
        for (int i = 0; i < 16; ++i) {
            int dl = w * 16 + i;
            WT[(size_t)(td * 64 + dl) * DM + te * 64 + lane] = tile[lane][dl];
        }
    } else {                              // --- qh (one wave per (q,e)) ---
        int idx = (bx - 256) * 4 + w;     // 0..8191
        int q = idx >> 9, e = idx & 511;
        const float scale = 22.627416997969522f;   // sqrt(512)
        const float4* qr = (const float4*)(query + (size_t)q * DM);
        float4 a0 = qr[lane * 2], a1 = qr[lane * 2 + 1];
        a0.x *= scale; a0.y *= scale; a0.z *= scale; a0.w *= scale;
        a1.x *= scale; a1.y *= scale; a1.z *= scale; a1.w *= scale;
        float s  = a0.x + a0.y + a0.z + a0.w + a1.x + a1.y + a1.z + a1.w;
        float s2 = a0.x * a0.x + a0.y * a0.y + a0.z * a0.z + a0.w * a0.w
                 + a1.x * a1.x + a1.y * a1.y + a1.z * a1.z + a1.w * a1.w;
        s = wave_reduce_sum(s); s2 = wave_reduce_sum(s2);
        float m = s * (1.f / DM);
        float var = s2 * (1.f / DM) - m * m;
        float rstd = rsqrtf(var + 1e-5f);
        const float4* gw = (const float4*)ln_q_w;
        const float4* gb = (const float4*)ln_q_b;
        const float4* wr = (const float4*)(Wq + (size_t)e * DM);
        float4 w0 = gw[lane * 2], w1 = gw[lane * 2 + 1];
        float4 b0 = gb[lane * 2], b1 = gb[lane * 2 + 1];
        float4 W0 = wr[lane * 2], W1 = wr[lane * 2 + 1];
        float acc = ((a0.x - m) * rstd * w0.x + b0.x) * W0.x
                  + ((a0.y - m) * rstd * w0.y + b0.y) * W0.y
                  + ((a0.z - m) * rstd * w0.z + b0.z) * W0.z
                  + ((a0.w - m) * rstd * w0.w + b0.w) * W0.w
                  + ((a1.x - m) * rstd * w1.x + b1.x) * W1.x
                  + ((a1.y - m) * rstd * w1.y + b1.y) * W1.y
                  + ((a1.z - m) * rstd * w1.z + b1.z) * W1.z
                  + ((a1.w - m) * rstd * w1.w + b1.w) * W1.w;
        acc = wave_reduce_sum(acc);
        if (lane == 0) qh[q * DM + e] = acc + bq[e];
    }
}

// --- K3: A2[g][d] rows via contiguous WkT/WvT + distributed consts ---------
// Each (g,d) wave's lane0 owns exactly one d (and one e=d), so the consts
// sums distribute 1:1 as atomicAdds. k3->main kernel boundary guarantees
// completion before any consumer. (qt/A/wv arrays eliminated.)
__global__ void k3_qt(const float* __restrict__ qh, const float* __restrict__ WkT,
                      const float* __restrict__ Wo, const float* __restrict__ WvT,
                      const float* __restrict__ lnw, const float* __restrict__ lnb,
                      const float* __restrict__ bk, const float* __restrict__ bv,
                      f32x2* __restrict__ A2, float* __restrict__ consts) {
    int idx = blockIdx.x * 4 + (threadIdx.x >> 6);   // 0..8703
    int lane = threadIdx.x & 63;
    int g = idx >> 9, d = idx & 511;
    const float4* wr;
    const float4* xr;
    if (g < NQ) {
        wr = (const float4*)(WkT + (size_t)d * DM);
        xr = (const float4*)(qh + (size_t)g * DM);
    } else {
        wr = (const float4*)(WvT + (size_t)d * DM);
        xr = (const float4*)Wo;
    }
    float4 w0 = wr[lane * 2], w1 = wr[lane * 2 + 1];
    float4 x0 = xr[lane * 2], x1 = xr[lane * 2 + 1];
    float s = w0.x * x0.x + w0.y * x0.y + w0.z * x0.z + w0.w * x0.w
            + w1.x * x1.x + w1.y * x1.y + w1.z * x1.z + w1.w * x1.w;
    s = wave_reduce_sum(s);
    if (lane == 0) {
        float a = s * lnw[d];
        f32x2 ap; ap.x = a; ap.y = a;
        A2[(size_t)g * DM + d] = ap;
        if (g < NQ) {
            atomicAdd(&consts[g], a);
            atomicAdd(&consts[16 + g], s * lnb[d] + qh[(size_t)g * DM + d] * bk[d]);
        } else {
            atomicAdd(&consts[32], a);
            atomicAdd(&consts[33], s * lnb[d] + Wo[d] * bv[d]);
        }
    }
}

// --- MAIN: streaming + inline per-batch finalize/softmax -------------------
// 512 threads (8 waves x 64 d, full 512-d range), grid (N/128, B).
// After writing pbuf partials, blocks atomically count completion per b;
// the 4th (last) block for b runs finalize+softmax for that batch inline
// (threadFenceReduction pattern) -> no separate k_fin launch, tail work
// overlaps main execution, pbuf stays L2-hot. LDS: scs/vls alias red.
__launch_bounds__(512, 4)
__global__ void main_fused(const float* __restrict__ latents,
                           const float* __restrict__ PET,
                           const f32x2* __restrict__ A2,
                           float* __restrict__ pbuf,
                           int* __restrict__ cnt,
                           const float* __restrict__ consts,
                           const float* __restrict__ query_mask,
                           const float* __restrict__ bo,
                           float* __restrict__ out_logits,
                           float* __restrict__ out_attn, int N) {
    int lane = threadIdx.x & 63;
    int w = threadIdx.x >> 6;                 // 0..7
    int b = blockIdx.y;
    int ntile = blockIdx.x;
    int n0 = ntile * 128 + lane * 2;

    int d0 = __builtin_amdgcn_readfirstlane(w * 64);
    const float* latf = latents + (size_t)b * DM * N + (size_t)d0 * N + n0;
    const float* petf = PET + (size_t)d0 * N + n0;
    const float scale = 22.627416997969522f;
    f32x2 sc2; sc2.x = scale; sc2.y = scale;

    f32x2 acc[NG];
    #pragma unroll
    for (int i = 0; i < NG; ++i) { acc[i].x = 0.f; acc[i].y = 0.f; }
    f32x2 S1 = {0.f, 0.f}, S2 = {0.f, 0.f};

    const int U = 4;                 // d per chunk
    const int NC = 64 / U;           // 16 chunks
    f32x2 xb[2][U], pb[2][U];
    #pragma unroll
    for (int u = 0; u < U; ++u) {
        xb[0][u] = __builtin_nontemporal_load((const f32x2*)(latf + (size_t)u * N));
        pb[0][u] = *(const f32x2*)(petf + (size_t)u * N);
    }
    for (int c = 0; c < NC; c += 2) {         // explicit 2x unroll: cur/nxt static
        #pragma unroll
        for (int u = 0; u < U; ++u) {
            size_t dd = (size_t)((c + 1) * U + u) * N;
            xb[1][u] = __builtin_nontemporal_load((const f32x2*)(latf + dd));
            pb[1][u] = *(const f32x2*)(petf + dd);
        }
        #pragma unroll
        for (int u = 0; u < U; ++u) {
            f32x2 y = xb[0][u] * sc2 + pb[0][u];
            S1 += y; S2 += y * y;
            int d = d0 + c * U + u;
            #pragma unroll
            for (int q = 0; q < NG; ++q)
                acc[q] += A2[(size_t)q * DM + d] * y;
        }
        if (c + 2 < NC) {
            #pragma unroll
            for (int u = 0; u < U; ++u) {
                size_t dd = (size_t)((c + 2) * U + u) * N;
                xb[0][u] = __builtin_nontemporal_load((const f32x2*)(latf + dd));
                pb[0][u] = *(const f32x2*)(petf + dd);
            }
        }
        #pragma unroll
        for (int u = 0; u < U; ++u) {
            f32x2 y = xb[1][u] * sc2 + pb[1][u];
            S1 += y; S2 += y * y;
            int d = d0 + (c + 1) * U + u;
            #pragma unroll
            for (int q = 0; q < NG; ++q)
                acc[q] += A2[(size_t)q * DM + d] * y;
        }
    }

    // LDS union: red (38.9 KB) for the reduction; scs/vls (34.8 KB) alias it
    // in the finisher phase (red fully consumed before the alias is written).
    __shared__ __align__(16) char smem[4 * NR * 64 * sizeof(f32x2)];
    __shared__ int finflag;
    f32x2 (*red)[NR][64] = (f32x2 (*)[NR][64])smem;

    // 8-wave -> 4-slot two-phase reduction
    if (w >= 4) {
        int ww = w - 4;
        red[ww][0][lane] = S1;
        red[ww][1][lane] = S2;
        #pragma unroll
        for (int i = 0; i < NG; ++i) red[ww][2 + i][lane] = acc[i];
    }
    __syncthreads();
    if (w < 4) {
        red[w][0][lane] += S1;
        red[w][1][lane] += S2;
        #pragma unroll
        for (int i = 0; i < NG; ++i) red[w][2 + i][lane] += acc[i];
    }
    __syncthreads();
    if (w == 0) {
        float* pout = pbuf + ((size_t)b * NR) * N + n0;
        #pragma unroll
        for (int i = 0; i < NR; ++i) {
            f32x2 t = red[0][i][lane] + red[1][i][lane]
                    + red[2][i][lane] + red[3][i][lane];
            *(f32x2*)(pout + (size_t)i * N) = t;
        }
    }

    // --- completion counting (threadFenceReduction pattern) ---
    __threadfence();                 // make this block's pbuf writes visible
    __syncthreads();
    if (threadIdx.x == 0) finflag = atomicAdd(&cnt[b], 1);
    __syncthreads();
    if (finflag != 3) return;        // not the last producer for this b
    __threadfence();                 // acquire: other producers' pbuf writes

    // --- inline finalize + softmax for batch b ---
    float* scs = (float*)smem;                    // [NQ][512], aliases red
    float* vls = (float*)(smem + NQ * 512 * sizeof(float));
    int tid = threadIdx.x;
    const float isd = 0.044194173824159216f;      // 1/sqrt(512)
    float c32 = consts[32], c33 = consts[33];

    for (int np = tid; np < (N >> 1); np += 512) {
        int nn = np * 2;
        const float* p = pbuf + ((size_t)b * NR) * N + nn;
        f32x2 tot[NR];
        #pragma unroll
        for (int i = 0; i < NR; ++i) tot[i] = *(const f32x2*)(p + (size_t)i * N);
        f32x2 m = tot[0] * (1.f / DM);
        f32x2 ex2 = tot[1] * (1.f / DM);
        f32x2 rstd;
        rstd.x = rsqrtf(ex2.x - m.x * m.x + 1e-5f);
        rstd.y = rsqrtf(ex2.y - m.y * m.y + 1e-5f);
        f32x2 v = rstd * (tot[2 + NQ] - m * c32) + c33;
        *(f32x2*)&vls[nn] = v;
        #pragma unroll
        for (int q = 0; q < NQ; ++q) {
            f32x2 sc = (rstd * (tot[2 + q] - m * consts[q]) + consts[16 + q]) * isd;
            *(f32x2*)&scs[q * 512 + nn] = sc;
        }
    }
    __syncthreads();

    int nv = N >> 2;                      // f32x4 count per row
    for (int q = w; q < NQ; q += 8) {     // 8 waves -> 2 rows each
        int r = b * NQ + q;
        float qm = query_mask[r];
        f32x4* arow = (f32x4*)(out_attn + (size_t)r * N);
        if (qm == 0.f) {                  // fully masked: uniform weights, wiped logits
            float u = 1.f / (float)N;
            f32x4 uv; uv.x = u; uv.y = u; uv.z = u; uv.w = u;
            for (int i = lane; i < nv; i += 64)
                __builtin_nontemporal_store(uv, &arow[i]);
            if (lane == 0) out_logits[r] = bo[0];
            continue;
        }
        const f32x4* srow = (const f32x4*)(scs + q * 512);
        f32x4 sv[2];
        sv[0] = srow[lane]; sv[1] = srow[64 + lane];
        float mx = fmaxf(fmaxf(fmaxf(sv[0].x, sv[0].y), fmaxf(sv[0].z, sv[0].w)),
                         fmaxf(fmaxf(sv[1].x, sv[1].y), fmaxf(sv[1].z, sv[1].w)));
        mx = wave_reduce_max(mx);
        float sum = 0.f;
        #pragma unroll
        for (int i = 0; i < 2; ++i) {
            sv[i].x = expf(sv[i].x - mx); sv[i].y = expf(sv[i].y - mx);
            sv[i].z = expf(sv[i].z - mx); sv[i].w = expf(sv[i].w - mx);
            sum += sv[i].x + sv[i].y + sv[i].z + sv[i].w;
        }
        sum = wave_reduce_sum(sum);
        float inv = 1.f / sum;
        const f32x4* vrow = (const f32x4*)vls;
        float lp = 0.f;
        #pragma unroll
        for (int i = 0; i < 2; ++i) {
            f32x4 vv = vrow[i * 64 + lane];
            f32x4 wgt = sv[i] * inv;
            __builtin_nontemporal_store(wgt, &arow[i * 64 + lane]);
            lp += wgt.x * vv.x + wgt.y * vv.y + wgt.z * vv.z + wgt.w * vv.w;
        }
        lp = wave_reduce_sum(lp);
        if (lane == 0) out_logits[r] = lp + bo[0];
    }
}

extern "C" void kernel_launch(void* const* d_in, const int* in_sizes, int n_in,
                              void* d_out, int out_size, void* d_ws, size_t ws_size,
                              hipStream_t stream) {
    const float* latents    = (const float*)d_in[0];
    const float* query_mask = (const float*)d_in[1];
    const float* query      = (const float*)d_in[2];
    const float* ln_lat_w   = (const float*)d_in[3];
    const float* ln_lat_b   = (const float*)d_in[4];
    const float* ln_q_w     = (const float*)d_in[5];
    const float* ln_q_b     = (const float*)d_in[6];
    const float* Wq         = (const float*)d_in[7];
    const float* bq         = (const float*)d_in[8];
    const float* Wk         = (const float*)d_in[9];
    const float* bk         = (const float*)d_in[10];
    const float* Wv         = (const float*)d_in[11];
    const float* bv         = (const float*)d_in[12];
    const float* Wo         = (const float*)d_in[13];
    const float* bo         = (const float*)d_in[14];

    int B = in_sizes[1] / NQ;
    int N = in_sizes[0] / (DM * B);

    float* ws = (float*)d_ws;
    size_t off = 0;
    float* PET    = ws + off; off += (size_t)DM * N;
    float* WkT    = ws + off; off += (size_t)DM * DM;
    float* WvT    = ws + off; off += (size_t)DM * DM;
    float* qh     = ws + off; off += NQ * DM;
    float* A2     = ws + off; off += (size_t)NG * DM * 2;
    float* consts = ws + off; off += 64;
    int*   cnt    = (int*)(ws + off); off += 128;
    float* pbuf   = ws + off; off += (size_t)B * NR * N;

    float* out_logits = (float*)d_out;
    float* out_attn   = out_logits + (size_t)B * NQ;

    k1_setup<<<256 + NQ * DM / 4, 256, 0, stream>>>(
        Wk, Wv, query, ln_q_w, ln_q_b, Wq, bq, PET, WkT, WvT, qh,
        consts, cnt, N, B);
    k3_qt<<<NG * DM / 4, 256, 0, stream>>>(qh, WkT, Wo, WvT, ln_lat_w, ln_lat_b,
                                           bk, bv, (f32x2*)A2, consts);
    dim3 gmain(N >> 7, B);
    main_fused<<<gmain, 512, 0, stream>>>(latents, PET, (const f32x2*)A2,
                                          pbuf, cnt, consts, query_mask, bo,
                                          out_logits, out_attn, N);
}

// Round 7
// 382.578 us; speedup vs baseline: 1.3298x; 1.3298x over previous
//
#include <hip/hip_runtime.h>
#include <math.h>

#define DM 512          // d_model
#define NQ 16           // num output queries
#define NG (NQ + 1)     // 16 score rows + 1 pooled-v row
#define NR (NG + 2)     // 19 partial rows: S1, S2, acc[0..16]

typedef __attribute__((ext_vector_type(2))) float f32x2;
typedef __attribute__((ext_vector_type(4))) float f32x4;   // clang-native: OK for nontemporal builtins

__device__ __forceinline__ float wave_reduce_sum(float v) {
    #pragma unroll
    for (int off = 32; off > 0; off >>= 1) v += __shfl_xor(v, off, 64);
    return v;
}
__device__ __forceinline__ float wave_reduce_max(float v) {
    #pragma unroll
    for (int off = 32; off > 0; off >>= 1) v = fmaxf(v, __shfl_xor(v, off, 64));
    return v;
}

// --- K1: fused independent precompute --------------------------------------
// blocks 0..127   : PET[d][n] generation (block 0 also zeroes consts)
// blocks 128..255 : LDS-tiled transpose Wk->WkT, Wv->WvT
// blocks 256..2303: qh[q][e] = LN(query[q]*scale) . Wq[e] + bq[e]
__global__ void k1_setup(const float* __restrict__ Wk, const float* __restrict__ Wv,
                         const float* __restrict__ query,
                         const float* __restrict__ ln_q_w, const float* __restrict__ ln_q_b,
                         const float* __restrict__ Wq, const float* __restrict__ bq,
                         float* __restrict__ PET, float* __restrict__ WkT,
                         float* __restrict__ WvT, float* __restrict__ qh,
                         float* __restrict__ consts, int N) {
    __shared__ float tile[64][65];
    int bx = blockIdx.x;
    int lane = threadIdx.x & 63;
    int w = threadIdx.x >> 6;

    if (bx < 128) {                       // --- PET (+ consts zero on block 0) ---
        if (bx == 0 && threadIdx.x < 34) consts[threadIdx.x] = 0.f;
        int ntile = bx & 7, jg = bx >> 3;
        int n = ntile * 64 + lane;
        float p = (float)(N - 1 - n);     // reversed PE
        const float c = -logf(10000.f) / (float)DM;
        int jbase = jg * 16 + w * 4;
        #pragma unroll
        for (int u = 0; u < 4; ++u) {
            int j = jbase + u;
            float wj = expf((float)(2 * j) * c);
            float ang = p * wj;
            PET[(size_t)(2 * j) * N + n] = sinf(ang);
            PET[(size_t)(2 * j + 1) * N + n] = cosf(ang);
        }
    } else if (bx < 256) {                // --- transpose ---
        int t = bx - 128;
        const float* W = (t >> 6) ? Wv : Wk;
        float* WT = (t >> 6) ? WvT : WkT;
        int tl = t & 63;
        int te = tl >> 3, td = tl & 7;    // 8x8 tiles of 64x64
        #pragma unroll
        for (int i = 0; i < 16; ++i) {
            int el = w * 16 + i;
            tile[el][lane] = W[(size_t)(te * 64 + el) * DM + td * 64 + lane];
        }
        __syncthreads();
        #pragma unroll
        for (int i = 0; i < 16; ++i) {
            int dl = w * 16 + i;
            WT[(size_t)(td * 64 + dl) * DM + te * 64 + lane] = tile[lane][dl];
        }
    } else {                              // --- qh (one wave per (q,e)) ---
        int idx = (bx - 256) * 4 + w;     // 0..8191
        int q = idx >> 9, e = idx & 511;
        const float scale = 22.627416997969522f;   // sqrt(512)
        const float4* qr = (const float4*)(query + (size_t)q * DM);
        float4 a0 = qr[lane * 2], a1 = qr[lane * 2 + 1];
        a0.x *= scale; a0.y *= scale; a0.z *= scale; a0.w *= scale;
        a1.x *= scale; a1.y *= scale; a1.z *= scale; a1.w *= scale;
        float s  = a0.x + a0.y + a0.z + a0.w + a1.x + a1.y + a1.z + a1.w;
        float s2 = a0.x * a0.x + a0.y * a0.y + a0.z * a0.z + a0.w * a0.w
                 + a1.x * a1.x + a1.y * a1.y + a1.z * a1.z + a1.w * a1.w;
        s = wave_reduce_sum(s); s2 = wave_reduce_sum(s2);
        float m = s * (1.f / DM);
        float var = s2 * (1.f / DM) - m * m;
        float rstd = rsqrtf(var + 1e-5f);
        const float4* gw = (const float4*)ln_q_w;
        const float4* gb = (const float4*)ln_q_b;
        const float4* wr = (const float4*)(Wq + (size_t)e * DM);
        float4 w0 = gw[lane * 2], w1 = gw[lane * 2 + 1];
        float4 b0 = gb[lane * 2], b1 = gb[lane * 2 + 1];
        float4 W0 = wr[lane * 2], W1 = wr[lane * 2 + 1];
        float acc = ((a0.x - m) * rstd * w0.x + b0.x) * W0.x
                  + ((a0.y - m) * rstd * w0.y + b0.y) * W0.y
                  + ((a0.z - m) * rstd * w0.z + b0.z) * W0.z
                  + ((a0.w - m) * rstd * w0.w + b0.w) * W0.w
                  + ((a1.x - m) * rstd * w1.x + b1.x) * W1.x
                  + ((a1.y - m) * rstd * w1.y + b1.y) * W1.y
                  + ((a1.z - m) * rstd * w1.z + b1.z) * W1.z
                  + ((a1.w - m) * rstd * w1.w + b1.w) * W1.w;
        acc = wave_reduce_sum(acc);
        if (lane == 0) qh[q * DM + e] = acc + bq[e];
    }
}

// --- K3: A2[g][d] rows via contiguous WkT/WvT + distributed consts ---------
// Each (g,d) wave's lane0 owns exactly one d, so the consts sums distribute
// 1:1 as atomicAdds (zeroed by k1; k3->main kernel boundary = completion).
__global__ void k3_qt(const float* __restrict__ qh, const float* __restrict__ WkT,
                      const float* __restrict__ Wo, const float* __restrict__ WvT,
                      const float* __restrict__ lnw, const float* __restrict__ lnb,
                      const float* __restrict__ bk, const float* __restrict__ bv,
                      f32x2* __restrict__ A2, float* __restrict__ consts) {
    int idx = blockIdx.x * 4 + (threadIdx.x >> 6);   // 0..8703
    int lane = threadIdx.x & 63;
    int g = idx >> 9, d = idx & 511;
    const float4* wr;
    const float4* xr;
    if (g < NQ) {
        wr = (const float4*)(WkT + (size_t)d * DM);
        xr = (const float4*)(qh + (size_t)g * DM);
    } else {
        wr = (const float4*)(WvT + (size_t)d * DM);
        xr = (const float4*)Wo;
    }
    float4 w0 = wr[lane * 2], w1 = wr[lane * 2 + 1];
    float4 x0 = xr[lane * 2], x1 = xr[lane * 2 + 1];
    float s = w0.x * x0.x + w0.y * x0.y + w0.z * x0.z + w0.w * x0.w
            + w1.x * x1.x + w1.y * x1.y + w1.z * x1.z + w1.w * x1.w;
    s = wave_reduce_sum(s);
    if (lane == 0) {
        float a = s * lnw[d];
        f32x2 ap; ap.x = a; ap.y = a;
        A2[(size_t)g * DM + d] = ap;
        if (g < NQ) {
            atomicAdd(&consts[g], a);
            atomicAdd(&consts[16 + g], s * lnb[d] + qh[(size_t)g * DM + d] * bk[d]);
        } else {
            atomicAdd(&consts[32], a);
            atomicAdd(&consts[33], s * lnb[d] + Wo[d] * bv[d]);
        }
    }
}

// --- K5: main streaming (FULL-d blocks, no rider) --------------------------
// lane = 2 adjacent n (f32x2); 8 waves x 64 d cover the whole 512-d range.
// y = scale*x + pe in-register; rows: S1=sum y, S2=sum y^2, acc[g]=sum A*y.
// Packed f32x2 math, A broadcast from duplicated A2 (uniform addr -> s_load).
// KEEP THIS KERNEL TAIL-FREE: round 6 showed fusing the finalize tail in
// collapses regalloc (VGPR 48 + acc spilled to scratch, 8x slowdown).
__launch_bounds__(512, 4)
__global__ void main2_kernel(const float* __restrict__ latents,
                             const float* __restrict__ PET,
                             const f32x2* __restrict__ A2,
                             float* __restrict__ pbuf, int N) {
    int lane = threadIdx.x & 63;
    int w = threadIdx.x >> 6;                 // 0..7
    int b = blockIdx.y;
    int ntile = blockIdx.x;
    int n0 = ntile * 128 + lane * 2;

    int d0 = __builtin_amdgcn_readfirstlane(w * 64);
    const float* latf = latents + (size_t)b * DM * N + (size_t)d0 * N + n0;
    const float* petf = PET + (size_t)d0 * N + n0;
    const float scale = 22.627416997969522f;
    f32x2 sc2; sc2.x = scale; sc2.y = scale;

    f32x2 acc[NG];
    #pragma unroll
    for (int i = 0; i < NG; ++i) { acc[i].x = 0.f; acc[i].y = 0.f; }
    f32x2 S1 = {0.f, 0.f}, S2 = {0.f, 0.f};

    const int U = 4;                 // d per chunk
    const int NC = 64 / U;           // 16 chunks
    f32x2 xb[2][U], pb[2][U];
    #pragma unroll
    for (int u = 0; u < U; ++u) {
        xb[0][u] = __builtin_nontemporal_load((const f32x2*)(latf + (size_t)u * N));
        pb[0][u] = *(const f32x2*)(petf + (size_t)u * N);
    }
    for (int c = 0; c < NC; c += 2) {         // explicit 2x unroll: cur/nxt static
        #pragma unroll
        for (int u = 0; u < U; ++u) {
            size_t dd = (size_t)((c + 1) * U + u) * N;
            xb[1][u] = __builtin_nontemporal_load((const f32x2*)(latf + dd));
            pb[1][u] = *(const f32x2*)(petf + dd);
        }
        #pragma unroll
        for (int u = 0; u < U; ++u) {
            f32x2 y = xb[0][u] * sc2 + pb[0][u];
            S1 += y; S2 += y * y;
            int d = d0 + c * U + u;
            #pragma unroll
            for (int q = 0; q < NG; ++q)
                acc[q] += A2[(size_t)q * DM + d] * y;
        }
        if (c + 2 < NC) {
            #pragma unroll
            for (int u = 0; u < U; ++u) {
                size_t dd = (size_t)((c + 2) * U + u) * N;
                xb[0][u] = __builtin_nontemporal_load((const f32x2*)(latf + dd));
                pb[0][u] = *(const f32x2*)(petf + dd);
            }
        }
        #pragma unroll
        for (int u = 0; u < U; ++u) {
            f32x2 y = xb[1][u] * sc2 + pb[1][u];
            S1 += y; S2 += y * y;
            int d = d0 + (c + 1) * U + u;
            #pragma unroll
            for (int q = 0; q < NG; ++q)
                acc[q] += A2[(size_t)q * DM + d] * y;
        }
    }

    // 8-wave -> 4-slot two-phase reduction (static LDS 38.9 KB)
    __shared__ f32x2 red[4][NR][64];
    if (w >= 4) {
        int ww = w - 4;
        red[ww][0][lane] = S1;
        red[ww][1][lane] = S2;
        #pragma unroll
        for (int i = 0; i < NG; ++i) red[ww][2 + i][lane] = acc[i];
    }
    __syncthreads();
    if (w < 4) {
        red[w][0][lane] += S1;
        red[w][1][lane] += S2;
        #pragma unroll
        for (int i = 0; i < NG; ++i) red[w][2 + i][lane] += acc[i];
    }
    __syncthreads();
    if (w == 0) {
        float* pout = pbuf + ((size_t)b * NR) * N + n0;
        #pragma unroll
        for (int i = 0; i < NR; ++i) {
            f32x2 t = red[0][i][lane] + red[1][i][lane]
                    + red[2][i][lane] + red[3][i][lane];
            *(f32x2*)(pout + (size_t)i * N) = t;
        }
    }
}

// --- K6: fused finalize + softmax, one block per batch b --------------------
// phase 1: per n-pair LN math from full-d partials -> scores/v rows in LDS
// phase 2: wave-per-row softmax from LDS, nontemporal attn stores (f32x4) ---
__global__ void k_fin(const float* __restrict__ pbuf,
                      const float* __restrict__ consts,
                      const float* __restrict__ query_mask,
                      const float* __restrict__ bo,
                      float* __restrict__ out_logits,
                      float* __restrict__ out_attn, int N, int B) {
    __shared__ float scs[NQ][512];
    __shared__ float vls[512];
    int b = blockIdx.x;
    int tid = threadIdx.x;
    const float isd = 0.044194173824159216f;  // 1/sqrt(512)
    float c32 = consts[32], c33 = consts[33];

    for (int np = tid; np < (N >> 1); np += 256) {
        int n0 = np * 2;
        const float* p = pbuf + ((size_t)b * NR) * N + n0;
        f32x2 tot[NR];
        #pragma unroll
        for (int i = 0; i < NR; ++i) tot[i] = *(const f32x2*)(p + (size_t)i * N);
        f32x2 m = tot[0] * (1.f / DM);
        f32x2 ex2 = tot[1] * (1.f / DM);
        f32x2 rstd;
        rstd.x = rsqrtf(ex2.x - m.x * m.x + 1e-5f);
        rstd.y = rsqrtf(ex2.y - m.y * m.y + 1e-5f);
        f32x2 v = rstd * (tot[2 + NQ] - m * c32) + c33;
        *(f32x2*)&vls[n0] = v;
        #pragma unroll
        for (int q = 0; q < NQ; ++q) {
            f32x2 sc = (rstd * (tot[2 + q] - m * consts[q]) + consts[16 + q]) * isd;
            *(f32x2*)&scs[q][n0] = sc;
        }
    }
    __syncthreads();

    int lane = tid & 63, w = tid >> 6;
    int nv = N >> 2;                      // f32x4 count per row
    for (int q = w; q < NQ; q += 4) {
        int r = b * NQ + q;
        float qm = query_mask[r];
        f32x4* arow = (f32x4*)(out_attn + (size_t)r * N);
        if (qm == 0.f) {                  // fully masked: uniform weights, wiped logits
            float u = 1.f / (float)N;
            f32x4 uv; uv.x = u; uv.y = u; uv.z = u; uv.w = u;
            for (int i = lane; i < nv; i += 64)
                __builtin_nontemporal_store(uv, &arow[i]);
            if (lane == 0) out_logits[r] = bo[0];
            continue;
        }
        const f32x4* srow = (const f32x4*)scs[q];
        f32x4 sv[2];
        sv[0] = srow[lane]; sv[1] = srow[64 + lane];
        float mx = fmaxf(fmaxf(fmaxf(sv[0].x, sv[0].y), fmaxf(sv[0].z, sv[0].w)),
                         fmaxf(fmaxf(sv[1].x, sv[1].y), fmaxf(sv[1].z, sv[1].w)));
        mx = wave_reduce_max(mx);
        float sum = 0.f;
        #pragma unroll
        for (int i = 0; i < 2; ++i) {
            sv[i].x = expf(sv[i].x - mx); sv[i].y = expf(sv[i].y - mx);
            sv[i].z = expf(sv[i].z - mx); sv[i].w = expf(sv[i].w - mx);
            sum += sv[i].x + sv[i].y + sv[i].z + sv[i].w;
        }
        sum = wave_reduce_sum(sum);
        float inv = 1.f / sum;
        const f32x4* vrow = (const f32x4*)vls;
        float lp = 0.f;
        #pragma unroll
        for (int i = 0; i < 2; ++i) {
            f32x4 vv = vrow[i * 64 + lane];
            f32x4 wgt = sv[i] * inv;
            __builtin_nontemporal_store(wgt, &arow[i * 64 + lane]);
            lp += wgt.x * vv.x + wgt.y * vv.y + wgt.z * vv.z + wgt.w * vv.w;
        }
        lp = wave_reduce_sum(lp);
        if (lane == 0) out_logits[r] = lp + bo[0];
    }
}

extern "C" void kernel_launch(void* const* d_in, const int* in_sizes, int n_in,
                              void* d_out, int out_size, void* d_ws, size_t ws_size,
                              hipStream_t stream) {
    const float* latents    = (const float*)d_in[0];
    const float* query_mask = (const float*)d_in[1];
    const float* query      = (const float*)d_in[2];
    const float* ln_lat_w   = (const float*)d_in[3];
    const float* ln_lat_b   = (const float*)d_in[4];
    const float* ln_q_w     = (const float*)d_in[5];
    const float* ln_q_b     = (const float*)d_in[6];
    const float* Wq         = (const float*)d_in[7];
    const float* bq         = (const float*)d_in[8];
    const float* Wk         = (const float*)d_in[9];
    const float* bk         = (const float*)d_in[10];
    const float* Wv         = (const float*)d_in[11];
    const float* bv         = (const float*)d_in[12];
    const float* Wo         = (const float*)d_in[13];
    const float* bo         = (const float*)d_in[14];

    int B = in_sizes[1] / NQ;
    int N = in_sizes[0] / (DM * B);

    float* ws = (float*)d_ws;
    size_t off = 0;
    float* PET    = ws + off; off += (size_t)DM * N;
    float* WkT    = ws + off; off += (size_t)DM * DM;
    float* WvT    = ws + off; off += (size_t)DM * DM;
    float* qh     = ws + off; off += NQ * DM;
    float* A2     = ws + off; off += (size_t)NG * DM * 2;
    float* consts = ws + off; off += 64;
    float* pbuf   = ws + off; off += (size_t)B * NR * N;

    float* out_logits = (float*)d_out;
    float* out_attn   = out_logits + (size_t)B * NQ;

    k1_setup<<<256 + NQ * DM / 4, 256, 0, stream>>>(
        Wk, Wv, query, ln_q_w, ln_q_b, Wq, bq, PET, WkT, WvT, qh, consts, N);
    k3_qt<<<NG * DM / 4, 256, 0, stream>>>(qh, WkT, Wo, WvT, ln_lat_w, ln_lat_b,
                                           bk, bv, (f32x2*)A2, consts);
    dim3 gmain(N >> 7, B);
    main2_kernel<<<gmain, 512, 0, stream>>>(latents, PET, (const f32x2*)A2,
                                            pbuf, N);
    k_fin<<<B, 256, 0, stream>>>(pbuf, consts, query_mask, bo,
                                 out_logits, out_attn, N, B);
}

// Round 8
// 238.712 us; speedup vs baseline: 2.1312x; 1.6027x over previous
//
#include <hip/hip_runtime.h>
#include <math.h>

#define DM 512          // d_model
#define NQ 16           // num output queries
#define NG (NQ + 1)     // 16 score rows + 1 pooled-v row
#define NR (NG + 2)     // 19 partial rows: S1, S2, acc[0..16]

typedef __attribute__((ext_vector_type(2))) float f32x2;
typedef __attribute__((ext_vector_type(4))) float f32x4;   // clang-native: OK for nontemporal builtins

__device__ __forceinline__ float wave_reduce_sum(float v) {
    #pragma unroll
    for (int off = 32; off > 0; off >>= 1) v += __shfl_xor(v, off, 64);
    return v;
}
__device__ __forceinline__ float wave_reduce_max(float v) {
    #pragma unroll
    for (int off = 32; off > 0; off >>= 1) v = fmaxf(v, __shfl_xor(v, off, 64));
    return v;
}

// --- K1: fused independent precompute --------------------------------------
// blocks 0..127   : PET[d][n] generation (8 n-tiles x 16 j-groups)
// blocks 128..255 : LDS-tiled transpose Wk->WkT, Wv->WvT
// blocks 256..2303: qh[q][e] = LN(query[q]*scale) . Wq[e] + bq[e]
//                   (query-LN recomputed per wave in registers)
__global__ void k1_setup(const float* __restrict__ Wk, const float* __restrict__ Wv,
                         const float* __restrict__ query,
                         const float* __restrict__ ln_q_w, const float* __restrict__ ln_q_b,
                         const float* __restrict__ Wq, const float* __restrict__ bq,
                         float* __restrict__ PET, float* __restrict__ WkT,
                         float* __restrict__ WvT, float* __restrict__ qh, int N) {
    __shared__ float tile[64][65];
    int bx = blockIdx.x;
    int lane = threadIdx.x & 63;
    int w = threadIdx.x >> 6;

    if (bx < 128) {                       // --- PET ---
        int ntile = bx & 7, jg = bx >> 3;
        int n = ntile * 64 + lane;
        float p = (float)(N - 1 - n);     // reversed PE
        const float c = -logf(10000.f) / (float)DM;
        int jbase = jg * 16 + w * 4;
        #pragma unroll
        for (int u = 0; u < 4; ++u) {
            int j = jbase + u;
            float wj = expf((float)(2 * j) * c);
            float ang = p * wj;
            PET[(size_t)(2 * j) * N + n] = sinf(ang);
            PET[(size_t)(2 * j + 1) * N + n] = cosf(ang);
        }
    } else if (bx < 256) {                // --- transpose ---
        int t = bx - 128;
        const float* W = (t >> 6) ? Wv : Wk;
        float* WT = (t >> 6) ? WvT : WkT;
        int tl = t & 63;
        int te = tl >> 3, td = tl & 7;    // 8x8 tiles of 64x64
        #pragma unroll
        for (int i = 0; i < 16; ++i) {
            int el = w * 16 + i;
            tile[el][lane] = W[(size_t)(te * 64 + el) * DM + td * 64 + lane];
        }
        __syncthreads();
        #pragma unroll
        for (int i = 0; i < 16; ++i) {
            int dl = w * 16 + i;
            WT[(size_t)(td * 64 + dl) * DM + te * 64 + lane] = tile[lane][dl];
        }
    } else {                              // --- qh (one wave per (q,e)) ---
        int idx = (bx - 256) * 4 + w;     // 0..8191
        int q = idx >> 9, e = idx & 511;
        const float scale = 22.627416997969522f;   // sqrt(512)
        const float4* qr = (const float4*)(query + (size_t)q * DM);
        float4 a0 = qr[lane * 2], a1 = qr[lane * 2 + 1];
        a0.x *= scale; a0.y *= scale; a0.z *= scale; a0.w *= scale;
        a1.x *= scale; a1.y *= scale; a1.z *= scale; a1.w *= scale;
        float s  = a0.x + a0.y + a0.z + a0.w + a1.x + a1.y + a1.z + a1.w;
        float s2 = a0.x * a0.x + a0.y * a0.y + a0.z * a0.z + a0.w * a0.w
                 + a1.x * a1.x + a1.y * a1.y + a1.z * a1.z + a1.w * a1.w;
        s = wave_reduce_sum(s); s2 = wave_reduce_sum(s2);
        float m = s * (1.f / DM);
        float var = s2 * (1.f / DM) - m * m;
        float rstd = rsqrtf(var + 1e-5f);
        const float4* gw = (const float4*)ln_q_w;
        const float4* gb = (const float4*)ln_q_b;
        const float4* wr = (const float4*)(Wq + (size_t)e * DM);
        float4 w0 = gw[lane * 2], w1 = gw[lane * 2 + 1];
        float4 b0 = gb[lane * 2], b1 = gb[lane * 2 + 1];
        float4 W0 = wr[lane * 2], W1 = wr[lane * 2 + 1];
        float acc = ((a0.x - m) * rstd * w0.x + b0.x) * W0.x
                  + ((a0.y - m) * rstd * w0.y + b0.y) * W0.y
                  + ((a0.z - m) * rstd * w0.z + b0.z) * W0.z
                  + ((a0.w - m) * rstd * w0.w + b0.w) * W0.w
                  + ((a1.x - m) * rstd * w1.x + b1.x) * W1.x
                  + ((a1.y - m) * rstd * w1.y + b1.y) * W1.y
                  + ((a1.z - m) * rstd * w1.z + b1.z) * W1.z
                  + ((a1.w - m) * rstd * w1.w + b1.w) * W1.w;
        acc = wave_reduce_sum(acc);
        if (lane == 0) qh[q * DM + e] = acc + bq[e];
    }
}

// --- K3: qt[g][d] (g<16) and wv[d] (g=16) via contiguous WkT/WvT rows ------
//         A[g][d] = coeff * ln_lat_w[d]; A2 = duplicated pair for pk_fma ----
// NOTE: consts sums stay in the main-grid rider (one store per wave, zero
// contention). Round 7 showed per-wave atomicAdd onto the 34-float consts
// block serializes cross-XCD at ~9ns/atomic -> 148us. Don't do that.
__global__ void k3_qt(const float* __restrict__ qh, const float* __restrict__ WkT,
                      const float* __restrict__ Wo, const float* __restrict__ WvT,
                      const float* __restrict__ lnw,
                      float* __restrict__ qt, float* __restrict__ A,
                      f32x2* __restrict__ A2, float* __restrict__ wvout) {
    int idx = blockIdx.x * 4 + (threadIdx.x >> 6);   // 0..8703
    int lane = threadIdx.x & 63;
    int g = idx >> 9, d = idx & 511;
    const float4* wr;
    const float4* xr;
    if (g < NQ) {
        wr = (const float4*)(WkT + (size_t)d * DM);
        xr = (const float4*)(qh + (size_t)g * DM);
    } else {
        wr = (const float4*)(WvT + (size_t)d * DM);
        xr = (const float4*)Wo;
    }
    float4 w0 = wr[lane * 2], w1 = wr[lane * 2 + 1];
    float4 x0 = xr[lane * 2], x1 = xr[lane * 2 + 1];
    float s = w0.x * x0.x + w0.y * x0.y + w0.z * x0.z + w0.w * x0.w
            + w1.x * x1.x + w1.y * x1.y + w1.z * x1.z + w1.w * x1.w;
    s = wave_reduce_sum(s);
    if (lane == 0) {
        if (g < NQ) qt[g * DM + d] = s;
        else wvout[d] = s;
        float a = s * lnw[d];
        A[g * DM + d] = a;
        f32x2 ap; ap.x = a; ap.y = a;
        A2[g * DM + d] = ap;
    }
}

// --- K5: main streaming (FULL-d blocks) + consts rider row -----------------
// blockIdx.y < B : lane = 2 adjacent n (f32x2); 8 waves x 64 d cover the
//   whole 512-d range -> single pbuf partial set (19 rows). y = scale*x + pe
//   in-register; rows: S1=sum y, S2=sum y^2, acc[g]=sum A[g,d]*y.
// blockIdx.y == B: rider blocks (17 active waves) compute consts.
// KEEP THIS KERNEL TAIL-FREE: round 6 showed fusing the finalize tail in
// collapses regalloc (VGPR 48 + acc spilled to scratch, 8x slowdown).
__launch_bounds__(512, 4)
__global__ void main2_kernel(const float* __restrict__ latents,
                             const float* __restrict__ PET,
                             const f32x2* __restrict__ A2,
                             const float* __restrict__ A,
                             const float* __restrict__ qt,
                             const float* __restrict__ qh,
                             const float* __restrict__ wv,
                             const float* __restrict__ lnb,
                             const float* __restrict__ bk,
                             const float* __restrict__ Wo,
                             const float* __restrict__ bv,
                             float* __restrict__ pbuf,
                             float* __restrict__ consts, int N) {
    int B = gridDim.y - 1;
    int lane = threadIdx.x & 63;
    int w = threadIdx.x >> 6;                 // 0..7
    int b = blockIdx.y;

    if (b == B) {                         // --- consts rider ---
        int t = blockIdx.x * 8 + w;       // 8 waves/block; valid t 0..16
        if (t > NQ) return;
        if (t < NQ) {
            float sa = 0.f, sc = 0.f, qb = 0.f;
            #pragma unroll
            for (int i = 0; i < 8; ++i) {
                int d = i * 64 + lane;
                sa += A[t * DM + d];
                sc = fmaf(qt[t * DM + d], lnb[d], sc);
                qb = fmaf(qh[t * DM + d], bk[d], qb);
            }
            sa = wave_reduce_sum(sa);
            sc = wave_reduce_sum(sc);
            qb = wave_reduce_sum(qb);
            if (lane == 0) { consts[t] = sa; consts[16 + t] = sc + qb; }
        } else {
            float sa = 0.f, cv = 0.f, bvo = 0.f;
            #pragma unroll
            for (int i = 0; i < 8; ++i) {
                int d = i * 64 + lane;
                sa += A[NQ * DM + d];
                cv = fmaf(wv[d], lnb[d], cv);
                bvo = fmaf(Wo[d], bv[d], bvo);
            }
            sa = wave_reduce_sum(sa);
            cv = wave_reduce_sum(cv);
            bvo = wave_reduce_sum(bvo);
            if (lane == 0) { consts[32] = sa; consts[33] = cv + bvo; }
        }
        return;
    }

    int ntile = blockIdx.x;
    int n0 = ntile * 128 + lane * 2;

    int d0 = __builtin_amdgcn_readfirstlane(w * 64);
    const float* latf = latents + (size_t)b * DM * N + (size_t)d0 * N + n0;
    const float* petf = PET + (size_t)d0 * N + n0;
    const float scale = 22.627416997969522f;
    f32x2 sc2; sc2.x = scale; sc2.y = scale;

    f32x2 acc[NG];
    #pragma unroll
    for (int i = 0; i < NG; ++i) { acc[i].x = 0.f; acc[i].y = 0.f; }
    f32x2 S1 = {0.f, 0.f}, S2 = {0.f, 0.f};

    const int U = 4;                 // d per chunk
    const int NC = 64 / U;           // 16 chunks
    f32x2 xb[2][U], pb[2][U];
    #pragma unroll
    for (int u = 0; u < U; ++u) {
        xb[0][u] = __builtin_nontemporal_load((const f32x2*)(latf + (size_t)u * N));
        pb[0][u] = *(const f32x2*)(petf + (size_t)u * N);
    }
    for (int c = 0; c < NC; c += 2) {         // explicit 2x unroll: cur/nxt static
        #pragma unroll
        for (int u = 0; u < U; ++u) {
            size_t dd = (size_t)((c + 1) * U + u) * N;
            xb[1][u] = __builtin_nontemporal_load((const f32x2*)(latf + dd));
            pb[1][u] = *(const f32x2*)(petf + dd);
        }
        #pragma unroll
        for (int u = 0; u < U; ++u) {
            f32x2 y = xb[0][u] * sc2 + pb[0][u];
            S1 += y; S2 += y * y;
            int d = d0 + c * U + u;
            #pragma unroll
            for (int q = 0; q < NG; ++q)
                acc[q] += A2[(size_t)q * DM + d] * y;
        }
        if (c + 2 < NC) {
            #pragma unroll
            for (int u = 0; u < U; ++u) {
                size_t dd = (size_t)((c + 2) * U + u) * N;
                xb[0][u] = __builtin_nontemporal_load((const f32x2*)(latf + dd));
                pb[0][u] = *(const f32x2*)(petf + dd);
            }
        }
        #pragma unroll
        for (int u = 0; u < U; ++u) {
            f32x2 y = xb[1][u] * sc2 + pb[1][u];
            S1 += y; S2 += y * y;
            int d = d0 + (c + 1) * U + u;
            #pragma unroll
            for (int q = 0; q < NG; ++q)
                acc[q] += A2[(size_t)q * DM + d] * y;
        }
    }

    // 8-wave -> 4-slot two-phase reduction (static LDS stays 38.9 KB)
    __shared__ f32x2 red[4][NR][64];
    if (w >= 4) {
        int ww = w - 4;
        red[ww][0][lane] = S1;
        red[ww][1][lane] = S2;
        #pragma unroll
        for (int i = 0; i < NG; ++i) red[ww][2 + i][lane] = acc[i];
    }
    __syncthreads();
    if (w < 4) {
        red[w][0][lane] += S1;
        red[w][1][lane] += S2;
        #pragma unroll
        for (int i = 0; i < NG; ++i) red[w][2 + i][lane] += acc[i];
    }
    __syncthreads();
    if (w == 0) {
        float* pout = pbuf + ((size_t)b * NR) * N + n0;
        #pragma unroll
        for (int i = 0; i < NR; ++i) {
            f32x2 t = red[0][i][lane] + red[1][i][lane]
                    + red[2][i][lane] + red[3][i][lane];
            *(f32x2*)(pout + (size_t)i * N) = t;
        }
    }
}

// --- K6: fused finalize + softmax, one block per batch b --------------------
// phase 1: per n-pair LN math from single full-d partials -> scores/v in LDS
// phase 2: wave-per-row softmax from LDS, nontemporal attn stores (f32x4) ---
__global__ void k_fin(const float* __restrict__ pbuf,
                      const float* __restrict__ consts,
                      const float* __restrict__ query_mask,
                      const float* __restrict__ bo,
                      float* __restrict__ out_logits,
                      float* __restrict__ out_attn, int N, int B) {
    __shared__ float scs[NQ][512];
    __shared__ float vls[512];
    int b = blockIdx.x;
    int tid = threadIdx.x;
    const float isd = 0.044194173824159216f;  // 1/sqrt(512)
    float c32 = consts[32], c33 = consts[33];

    for (int np = tid; np < (N >> 1); np += 256) {
        int n0 = np * 2;
        const float* p = pbuf + ((size_t)b * NR) * N + n0;
        f32x2 tot[NR];
        #pragma unroll
        for (int i = 0; i < NR; ++i) tot[i] = *(const f32x2*)(p + (size_t)i * N);
        f32x2 m = tot[0] * (1.f / DM);
        f32x2 ex2 = tot[1] * (1.f / DM);
        f32x2 rstd;
        rstd.x = rsqrtf(ex2.x - m.x * m.x + 1e-5f);
        rstd.y = rsqrtf(ex2.y - m.y * m.y + 1e-5f);
        f32x2 v = rstd * (tot[2 + NQ] - m * c32) + c33;
        *(f32x2*)&vls[n0] = v;
        #pragma unroll
        for (int q = 0; q < NQ; ++q) {
            f32x2 sc = (rstd * (tot[2 + q] - m * consts[q]) + consts[16 + q]) * isd;
            *(f32x2*)&scs[q][n0] = sc;
        }
    }
    __syncthreads();

    int lane = tid & 63, w = tid >> 6;
    int nv = N >> 2;                      // f32x4 count per row
    for (int q = w; q < NQ; q += 4) {
        int r = b * NQ + q;
        float qm = query_mask[r];
        f32x4* arow = (f32x4*)(out_attn + (size_t)r * N);
        if (qm == 0.f) {                  // fully masked: uniform weights, wiped logits
            float u = 1.f / (float)N;
            f32x4 uv; uv.x = u; uv.y = u; uv.z = u; uv.w = u;
            for (int i = lane; i < nv; i += 64)
                __builtin_nontemporal_store(uv, &arow[i]);
            if (lane == 0) out_logits[r] = bo[0];
            continue;
        }
        const f32x4* srow = (const f32x4*)scs[q];
        f32x4 sv[2];
        sv[0] = srow[lane]; sv[1] = srow[64 + lane];
        float mx = fmaxf(fmaxf(fmaxf(sv[0].x, sv[0].y), fmaxf(sv[0].z, sv[0].w)),
                         fmaxf(fmaxf(sv[1].x, sv[1].y), fmaxf(sv[1].z, sv[1].w)));
        mx = wave_reduce_max(mx);
        float sum = 0.f;
        #pragma unroll
        for (int i = 0; i < 2; ++i) {
            sv[i].x = expf(sv[i].x - mx); sv[i].y = expf(sv[i].y - mx);
            sv[i].z = expf(sv[i].z - mx); sv[i].w = expf(sv[i].w - mx);
            sum += sv[i].x + sv[i].y + sv[i].z + sv[i].w;
        }
        sum = wave_reduce_sum(sum);
        float inv = 1.f / sum;
        const f32x4* vrow = (const f32x4*)vls;
        float lp = 0.f;
        #pragma unroll
        for (int i = 0; i < 2; ++i) {
            f32x4 vv = vrow[i * 64 + lane];
            f32x4 wgt = sv[i] * inv;
            __builtin_nontemporal_store(wgt, &arow[i * 64 + lane]);
            lp += wgt.x * vv.x + wgt.y * vv.y + wgt.z * vv.z + wgt.w * vv.w;
        }
        lp = wave_reduce_sum(lp);
        if (lane == 0) out_logits[r] = lp + bo[0];
    }
}

extern "C" void kernel_launch(void* const* d_in, const int* in_sizes, int n_in,
                              void* d_out, int out_size, void* d_ws, size_t ws_size,
                              hipStream_t stream) {
    const float* latents    = (const float*)d_in[0];
    const float* query_mask = (const float*)d_in[1];
    const float* query      = (const float*)d_in[2];
    const float* ln_lat_w   = (const float*)d_in[3];
    const float* ln_lat_b   = (const float*)d_in[4];
    const float* ln_q_w     = (const float*)d_in[5];
    const float* ln_q_b     = (const float*)d_in[6];
    const float* Wq         = (const float*)d_in[7];
    const float* bq         = (const float*)d_in[8];
    const float* Wk         = (const float*)d_in[9];
    const float* bk         = (const float*)d_in[10];
    const float* Wv         = (const float*)d_in[11];
    const float* bv         = (const float*)d_in[12];
    const float* Wo         = (const float*)d_in[13];
    const float* bo         = (const float*)d_in[14];

    int B = in_sizes[1] / NQ;
    int N = in_sizes[0] / (DM * B);

    float* ws = (float*)d_ws;
    size_t off = 0;
    float* PET    = ws + off; off += (size_t)DM * N;
    float* WkT    = ws + off; off += (size_t)DM * DM;
    float* WvT    = ws + off; off += (size_t)DM * DM;
    float* qh     = ws + off; off += NQ * DM;
    float* qt     = ws + off; off += NQ * DM;
    float* A      = ws + off; off += NG * DM;
    float* A2     = ws + off; off += (size_t)NG * DM * 2;
    float* wv     = ws + off; off += DM;
    float* consts = ws + off; off += 64;
    float* pbuf   = ws + off; off += (size_t)B * NR * N;

    float* out_logits = (float*)d_out;
    float* out_attn   = out_logits + (size_t)B * NQ;

    k1_setup<<<256 + NQ * DM / 4, 256, 0, stream>>>(
        Wk, Wv, query, ln_q_w, ln_q_b, Wq, bq, PET, WkT, WvT, qh, N);
    k3_qt<<<NG * DM / 4, 256, 0, stream>>>(qh, WkT, Wo, WvT, ln_lat_w,
                                           qt, A, (f32x2*)A2, wv);
    dim3 gmain(N >> 7, B + 1);
    main2_kernel<<<gmain, 512, 0, stream>>>(latents, PET, (const f32x2*)A2,
                                            A, qt, qh, wv, ln_lat_b, bk, Wo, bv,
                                            pbuf, consts, N);
    k_fin<<<B, 256, 0, stream>>>(pbuf, consts, query_mask, bo,
                                 out_logits, out_attn, N, B);
}